// Round 1
// baseline (214.671 us; speedup 1.0000x reference)
//
#include <hip/hip_runtime.h>
#include <hip/hip_bf16.h>

#define T_WORDS 800000
#define S_SENT 2048
#define DIN 256
#define DOUT 128

typedef short bf16x8 __attribute__((ext_vector_type(8)));
typedef float f32x4 __attribute__((ext_vector_type(4)));

__device__ __forceinline__ unsigned short f2bf(float f) {
  unsigned int u = __builtin_bit_cast(unsigned int, f);
  u += 0x7fffu + ((u >> 16) & 1u);   // round-to-nearest-even
  return (unsigned short)(u >> 16);
}

// Prep: weight f32 -> bf16 into ws; sentence start offsets from sorted seg_ids.
__global__ void prep_kernel(const float* __restrict__ weight,
                            const int* __restrict__ seg,
                            unsigned short* __restrict__ wsB,
                            int* __restrict__ starts) {
  int tid = blockIdx.x * blockDim.x + threadIdx.x;
  int stride = gridDim.x * blockDim.x;
  for (int j = tid; j < DOUT * DIN; j += stride)
    wsB[j] = f2bf(weight[j]);
  for (int j = tid; j < T_WORDS; j += stride) {
    if (j == 0) {
      starts[seg[0]] = 0;
    } else {
      int s1 = seg[j], s0 = seg[j - 1];
      if (s1 != s0) starts[s1] = j;
    }
  }
}

// One block per sentence. 4 waves; wave w owns output cols [32w, 32w+32).
// Chunks of 64 words staged to LDS as bf16 (XOR-swizzled rows).
__global__ __launch_bounds__(256) void pool_kernel(
    const float* __restrict__ tokens,
    const float* __restrict__ bias,
    const unsigned short* __restrict__ wsB,
    const int* __restrict__ starts,
    const int* __restrict__ sent_batch,
    const int* __restrict__ sent_pos,
    float* __restrict__ out) {
  __shared__ alignas(16) unsigned short Alds[64 * DIN];  // 32 KB

  const int s = blockIdx.x;
  const int start = starts[s];
  const int end = (s == S_SENT - 1) ? T_WORDS : starts[s + 1];
  const int lane = (int)(threadIdx.x & 63);
  const int wv = (int)(threadIdx.x >> 6);

  // B fragments in registers: lane holds col = 16n + (lane&15), k = 8*(lane>>4)+j.
  // weight is [DOUT][DIN] row-major -> 8 consecutive k = 16B contiguous load.
  bf16x8 bfrag[2][8];
#pragma unroll
  for (int n = 0; n < 2; ++n) {
    const int col = 32 * wv + 16 * n + (lane & 15);
    const unsigned short* wrow = wsB + col * DIN + 8 * (lane >> 4);
#pragma unroll
    for (int kk = 0; kk < 8; ++kk)
      bfrag[n][kk] = *(const bf16x8*)(wrow + 32 * kk);
  }

  float runmax0 = -INFINITY, runmax1 = -INFINITY;

  for (int wbase = start; wbase < end; wbase += 64) {
    __syncthreads();  // protect LDS against previous-iteration readers
    // Stage 64 rows x 256 f32 -> bf16 LDS. Thread t handles 8-elem groups.
#pragma unroll
    for (int it = 0; it < 8; ++it) {
      int g = (int)threadIdx.x + 256 * it;
      int row = g >> 5, k8 = g & 31;
      int word = wbase + row;
      if (word < end) {
        const float4* src = (const float4*)(tokens + (size_t)word * DIN + k8 * 8);
        float4 f0 = src[0];
        float4 f1 = src[1];
        bf16x8 v;
        v[0] = (short)f2bf(f0.x); v[1] = (short)f2bf(f0.y);
        v[2] = (short)f2bf(f0.z); v[3] = (short)f2bf(f0.w);
        v[4] = (short)f2bf(f1.x); v[5] = (short)f2bf(f1.y);
        v[6] = (short)f2bf(f1.z); v[7] = (short)f2bf(f1.w);
        int idx = (row * DIN + k8 * 8) ^ ((row & 7) << 3);  // swizzle (ushort units)
        *(bf16x8*)&Alds[idx] = v;
      }
      // rows >= end stay garbage; masked at the fold below.
    }
    __syncthreads();

    f32x4 acc[4][2];
#pragma unroll
    for (int m = 0; m < 4; ++m)
#pragma unroll
      for (int n = 0; n < 2; ++n)
        acc[m][n] = (f32x4){0.f, 0.f, 0.f, 0.f};

#pragma unroll
    for (int m = 0; m < 4; ++m) {
      const int arow = 16 * m + (lane & 15);
      const int abase = arow * DIN + 8 * (lane >> 4);
      const int axor = (lane & 7) << 3;
#pragma unroll
      for (int kk = 0; kk < 8; ++kk) {
        bf16x8 a = *(const bf16x8*)&Alds[(abase + 32 * kk) ^ axor];
        acc[m][0] = __builtin_amdgcn_mfma_f32_16x16x32_bf16(a, bfrag[0][kk], acc[m][0], 0, 0, 0);
        acc[m][1] = __builtin_amdgcn_mfma_f32_16x16x32_bf16(a, bfrag[1][kk], acc[m][1], 0, 0, 0);
      }
    }

    // Fold into running max with row-validity mask.
    const int rbase = 4 * (lane >> 4);
#pragma unroll
    for (int m = 0; m < 4; ++m) {
      const int w0 = wbase + 16 * m + rbase;
#pragma unroll
      for (int r = 0; r < 4; ++r) {
        if (w0 + r < end) {
          runmax0 = fmaxf(runmax0, acc[m][0][r]);
          runmax1 = fmaxf(runmax1, acc[m][1][r]);
        }
      }
    }
  }

  // Reduce across the 4 row-groups (lanes differing in bits 4,5).
  runmax0 = fmaxf(runmax0, __shfl_xor(runmax0, 16, 64));
  runmax0 = fmaxf(runmax0, __shfl_xor(runmax0, 32, 64));
  runmax1 = fmaxf(runmax1, __shfl_xor(runmax1, 16, 64));
  runmax1 = fmaxf(runmax1, __shfl_xor(runmax1, 32, 64));

  if (lane < 16) {
    const int sb = sent_batch[s], sp = sent_pos[s];
    float* o = out + ((size_t)sb * 64 + sp) * DOUT;
    const int c0 = 32 * wv + lane;
    o[c0] = runmax0 + bias[c0];
    o[c0 + 16] = runmax1 + bias[c0 + 16];
  }
}

extern "C" void kernel_launch(void* const* d_in, const int* in_sizes, int n_in,
                              void* d_out, int out_size, void* d_ws, size_t ws_size,
                              hipStream_t stream) {
  const float* tokens = (const float*)d_in[0];
  const float* weight = (const float*)d_in[1];
  const float* bias   = (const float*)d_in[2];
  const int* seg      = (const int*)d_in[3];
  const int* sbatch   = (const int*)d_in[4];
  const int* spos     = (const int*)d_in[5];
  float* out = (float*)d_out;

  unsigned short* wsB = (unsigned short*)d_ws;                    // 64 KB bf16 weight
  int* starts = (int*)((char*)d_ws + DOUT * DIN * sizeof(unsigned short));  // 8 KB

  prep_kernel<<<512, 256, 0, stream>>>(weight, seg, wsB, starts);
  pool_kernel<<<S_SENT, 256, 0, stream>>>(tokens, bias, wsB, starts, sbatch, spos, out);
}

// Round 2
// 153.083 us; speedup vs baseline: 1.4023x; 1.4023x over previous
//
#include <hip/hip_runtime.h>
#include <hip/hip_bf16.h>

#define T_WORDS 800000
#define S_SENT 2048
#define DIN 256
#define DOUT 128
#define CHUNK 32

typedef short bf16x8 __attribute__((ext_vector_type(8)));
typedef float f32x4 __attribute__((ext_vector_type(4)));

__device__ __forceinline__ unsigned short f2bf(float f) {
  unsigned int u = __builtin_bit_cast(unsigned int, f);
  u += 0x7fffu + ((u >> 16) & 1u);   // round-to-nearest-even
  return (unsigned short)(u >> 16);
}

// Prep: weight f32 -> bf16 into ws; sentence start offsets from sorted seg_ids.
__global__ void prep_kernel(const float* __restrict__ weight,
                            const int* __restrict__ seg,
                            unsigned short* __restrict__ wsB,
                            int* __restrict__ starts) {
  int tid = blockIdx.x * blockDim.x + threadIdx.x;
  int stride = gridDim.x * blockDim.x;
  for (int j = tid; j < DOUT * DIN; j += stride)
    wsB[j] = f2bf(weight[j]);
  for (int j = tid; j < T_WORDS; j += stride) {
    if (j == 0) {
      starts[seg[0]] = 0;
    } else {
      int s1 = seg[j], s0 = seg[j - 1];
      if (s1 != s0) starts[s1] = j;
    }
  }
}

// One block per sentence. 4 waves; wave w owns output cols [32w, 32w+32).
// 32-row chunks, double-buffered LDS, T14 async-STAGE split:
//   issue loads(c+1) -> compute(c) -> cvt+write(c+1) -> barrier.
__global__ __launch_bounds__(256) void pool_kernel(
    const float* __restrict__ tokens,
    const float* __restrict__ bias,
    const unsigned short* __restrict__ wsB,
    const int* __restrict__ starts,
    const int* __restrict__ sent_batch,
    const int* __restrict__ sent_pos,
    float* __restrict__ out) {
  __shared__ alignas(16) unsigned short Alds[2][CHUNK * DIN];  // 2 x 16 KB

  const int s = blockIdx.x;
  const int start = starts[s];
  const int end = (s == S_SENT - 1) ? T_WORDS : starts[s + 1];
  const int lane = (int)(threadIdx.x & 63);
  const int wv = (int)(threadIdx.x >> 6);

  // B fragments in registers: lane holds col = 16n + (lane&15), k = 8*(lane>>4)+j.
  bf16x8 bfrag[2][8];
#pragma unroll
  for (int n = 0; n < 2; ++n) {
    const int col = 32 * wv + 16 * n + (lane & 15);
    const unsigned short* wrow = wsB + col * DIN + 8 * (lane >> 4);
#pragma unroll
    for (int kk = 0; kk < 8; ++kk)
      bfrag[n][kk] = *(const bf16x8*)(wrow + 32 * kk);
  }

  // Staging decomposition: thread t, iter it covers row = (t>>5) + 8*it,
  // cols [8*(t&31), 8*(t&31)+8) -> 2 float4 loads (32B contiguous per thread).
  const int srow0 = (int)(threadIdx.x >> 5);
  const int sk8 = (int)(threadIdx.x & 31);

  float runmax0 = -INFINITY, runmax1 = -INFINITY;
  float4 pf[4][2];

#define ISSUE_LOADS(WBASE)                                                    \
  {                                                                           \
    _Pragma("unroll") for (int it = 0; it < 4; ++it) {                        \
      int word = (WBASE) + srow0 + 8 * it;                                    \
      if (word < end) {                                                       \
        const float4* src =                                                   \
            (const float4*)(tokens + (size_t)word * DIN + sk8 * 8);           \
        pf[it][0] = src[0];                                                   \
        pf[it][1] = src[1];                                                   \
      }                                                                       \
    }                                                                         \
  }

#define WRITE_STAGE(BUF)                                                      \
  {                                                                           \
    _Pragma("unroll") for (int it = 0; it < 4; ++it) {                        \
      int row = srow0 + 8 * it;                                               \
      float4 f0 = pf[it][0], f1 = pf[it][1];                                  \
      bf16x8 v;                                                               \
      v[0] = (short)f2bf(f0.x); v[1] = (short)f2bf(f0.y);                     \
      v[2] = (short)f2bf(f0.z); v[3] = (short)f2bf(f0.w);                     \
      v[4] = (short)f2bf(f1.x); v[5] = (short)f2bf(f1.y);                     \
      v[6] = (short)f2bf(f1.z); v[7] = (short)f2bf(f1.w);                     \
      int idx = (row * DIN + sk8 * 8) ^ ((row & 7) << 3);                     \
      *(bf16x8*)&Alds[BUF][idx] = v;                                          \
    }                                                                         \
  }

#define COMPUTE(BUF, WBASE)                                                   \
  {                                                                           \
    _Pragma("unroll") for (int m = 0; m < 2; ++m) {                           \
      f32x4 acc0 = (f32x4){0.f, 0.f, 0.f, 0.f};                               \
      f32x4 acc1 = (f32x4){0.f, 0.f, 0.f, 0.f};                               \
      const int arow = 16 * m + (lane & 15);                                  \
      const int abase = arow * DIN + 8 * (lane >> 4);                         \
      const int axor = (lane & 7) << 3;                                       \
      _Pragma("unroll") for (int kk = 0; kk < 8; ++kk) {                      \
        bf16x8 a = *(const bf16x8*)&Alds[BUF][(abase + 32 * kk) ^ axor];      \
        acc0 = __builtin_amdgcn_mfma_f32_16x16x32_bf16(a, bfrag[0][kk], acc0, \
                                                       0, 0, 0);              \
        acc1 = __builtin_amdgcn_mfma_f32_16x16x32_bf16(a, bfrag[1][kk], acc1, \
                                                       0, 0, 0);              \
      }                                                                       \
      const int w0 = (WBASE) + 16 * m + 4 * (lane >> 4);                      \
      _Pragma("unroll") for (int r = 0; r < 4; ++r) {                         \
        if (w0 + r < end) {                                                   \
          runmax0 = fmaxf(runmax0, acc0[r]);                                  \
          runmax1 = fmaxf(runmax1, acc1[r]);                                  \
        }                                                                     \
      }                                                                       \
    }                                                                         \
  }

  const int nch = (end - start + CHUNK - 1) / CHUNK;

  // Prologue: stage chunk 0 into buffer 0.
  ISSUE_LOADS(start)
  WRITE_STAGE(0)
  __syncthreads();

  for (int c = 0; c < nch; ++c) {
    const int cur = c & 1;
    const int wbase = start + c * CHUNK;
    if (c + 1 < nch) ISSUE_LOADS(wbase + CHUNK)   // loads in flight during MFMA
    COMPUTE(cur, wbase)
    if (c + 1 < nch) WRITE_STAGE(cur ^ 1)
    __syncthreads();
  }

  // Reduce across the 4 row-groups (lanes differing in bits 4,5).
  runmax0 = fmaxf(runmax0, __shfl_xor(runmax0, 16, 64));
  runmax0 = fmaxf(runmax0, __shfl_xor(runmax0, 32, 64));
  runmax1 = fmaxf(runmax1, __shfl_xor(runmax1, 16, 64));
  runmax1 = fmaxf(runmax1, __shfl_xor(runmax1, 32, 64));

  if (lane < 16) {
    const int sb = sent_batch[s], sp = sent_pos[s];
    float* o = out + ((size_t)sb * 64 + sp) * DOUT;
    const int c0 = 32 * wv + lane;
    o[c0] = runmax0 + bias[c0];
    o[c0 + 16] = runmax1 + bias[c0 + 16];
  }
}

extern "C" void kernel_launch(void* const* d_in, const int* in_sizes, int n_in,
                              void* d_out, int out_size, void* d_ws, size_t ws_size,
                              hipStream_t stream) {
  const float* tokens = (const float*)d_in[0];
  const float* weight = (const float*)d_in[1];
  const float* bias   = (const float*)d_in[2];
  const int* seg      = (const int*)d_in[3];
  const int* sbatch   = (const int*)d_in[4];
  const int* spos     = (const int*)d_in[5];
  float* out = (float*)d_out;

  unsigned short* wsB = (unsigned short*)d_ws;                    // 64 KB bf16 weight
  int* starts = (int*)((char*)d_ws + DOUT * DIN * sizeof(unsigned short));  // 8 KB

  prep_kernel<<<512, 256, 0, stream>>>(weight, seg, wsB, starts);
  pool_kernel<<<S_SENT, 256, 0, stream>>>(tokens, bias, wsB, starts, sbatch, spos, out);
}